// Round 3
// baseline (690.026 us; speedup 1.0000x reference)
//
#include <hip/hip_runtime.h>

#define NEG_SLOPE 0.2f

typedef __attribute__((ext_vector_type(8))) short short8;
typedef __attribute__((ext_vector_type(4))) float v4f;

__device__ __forceinline__ float wave_red_sum(float v) {
    for (int o = 32; o > 0; o >>= 1) v += __shfl_xor(v, o, 64);
    return v;
}
__device__ __forceinline__ float wave_red_max(float v) {
    for (int o = 32; o > 0; o >>= 1) v = fmaxf(v, __shfl_xor(v, o, 64));
    return v;
}
__device__ __forceinline__ unsigned short f2bf(float f) {
    union { float f; unsigned int u; } x; x.f = f;
    unsigned int r = x.u + 0x7fffu + ((x.u >> 16) & 1u);
    return (unsigned short)(r >> 16);
}
__device__ __forceinline__ float bf2f(unsigned short b) {
    union { unsigned int u; float f; } x; x.u = ((unsigned int)b) << 16;
    return x.f;
}
__device__ __forceinline__ void split_bf(float v, unsigned short& hi, unsigned short& lo) {
    hi = f2bf(v);
    lo = f2bf(v - bf2f(hi));
}

// ---------------- mega1: fc (FB blocks) + hist (HB blocks) + wsplit (WB blocks) ----------------
// All three are mutually independent; fc is the HBM-bound long pole so its blocks go first.
__global__ __launch_bounds__(256) void mega1_kernel(
        const float* __restrict__ z, const float* __restrict__ fcw, const float* __restrict__ fcb,
        unsigned short* __restrict__ xhi, unsigned short* __restrict__ xlo, int R, int FB,
        const int* __restrict__ dst, int* __restrict__ cnt, int E, int HB,
        const float* __restrict__ W0, const float* __restrict__ W1, const float* __restrict__ W2,
        int n0, int n1, int n2, unsigned short* __restrict__ whi, unsigned short* __restrict__ wlo) {
    const int b = blockIdx.x;
    if (b < FB) {
        // fc: x[r] = relu(dot64(z, fc_w[r]) + fc_b[r]) -> bf16 hi/lo. 16 lanes/row, float4 loads.
        int t = b * 256 + threadIdx.x;
        int r = t >> 4;
        int j = t & 15;
        if (r >= R) return;
        float4 wz = ((const float4*)z)[j];
        float4 ww = ((const float4*)fcw)[r * 16 + j];
        float p = wz.x * ww.x + wz.y * ww.y + wz.z * ww.z + wz.w * ww.w;
        p += __shfl_xor(p, 1, 64);
        p += __shfl_xor(p, 2, 64);
        p += __shfl_xor(p, 4, 64);
        p += __shfl_xor(p, 8, 64);
        if (j == 0) {
            float v = p + fcb[r];
            v = v > 0.f ? v : 0.f;
            unsigned short hi, lo;
            split_bf(v, hi, lo);
            xhi[r] = hi;
            xlo[r] = lo;
        }
    } else if (b < FB + HB) {
        int e = (b - FB) * 256 + threadIdx.x;
        if (e < E) atomicAdd(&cnt[dst[e]], 1);
    } else {
        int i = (b - FB - HB) * 256 + threadIdx.x;
        int ntot = n0 + n1 + n2;
        if (i >= ntot) return;
        float v;
        if (i < n0) v = W0[i];
        else if (i < n0 + n1) v = W1[i - n0];
        else v = W2[i - n0 - n1];
        unsigned short hi, lo;
        split_bf(v, hi, lo);
        whi[i] = hi;
        wlo[i] = lo;
    }
}

// ---------------- single-block exclusive scan over cnt[0..N) -> rowptr, cursor ----------------
__global__ __launch_bounds__(1024) void scan_kernel(const int* __restrict__ cnt,
                                                    int* __restrict__ rowptr,
                                                    int* __restrict__ cursor, int N) {
    constexpr int CH = 20;  // 1024*20 = 20480 >= N
    __shared__ int wsum[16];
    const int t = threadIdx.x;
    const int lane = t & 63, wid = t >> 6;
    const int base = t * CH;
    int loc[CH];
    int s = 0;
#pragma unroll
    for (int i = 0; i < CH; i++) {
        int idx = base + i;
        loc[i] = (idx < N) ? cnt[idx] : 0;
        s += loc[i];
    }
    int v = s;  // inclusive wave scan
    for (int off = 1; off < 64; off <<= 1) {
        int n = __shfl_up(v, off, 64);
        if (lane >= off) v += n;
    }
    if (lane == 63) wsum[wid] = v;
    __syncthreads();
    int woff = 0;
    for (int i = 0; i < wid; i++) woff += wsum[i];
    int excl = woff + v - s;
#pragma unroll
    for (int i = 0; i < CH; i++) {
        int idx = base + i;
        if (idx < N) { rowptr[idx] = excl; cursor[idx] = excl; }
        excl += loc[i];
    }
    if (t == 1023) rowptr[N] = excl;
}

// ---------------- gemm+att body (bf16-split MFMA, fragments straight from global) ----------------
// A-frag: A[m=lane&15][k=quad*8+j]; B-frag: B[k][n=lane&15]=W[n][k]; C/D: col=l15, row=quad*4+reg.
template <int FIN, int FOUT>
__device__ __forceinline__ void gemm_att_body(
        int wid, int lane, const unsigned short* __restrict__ xhi,
        const unsigned short* __restrict__ xlo, const unsigned short* __restrict__ whi,
        const unsigned short* __restrict__ wlo, const float* __restrict__ as,
        const float* __restrict__ ad, float* __restrict__ h, float* __restrict__ hs,
        float* __restrict__ hd, int Mtiles) {
    constexpr int NT = FOUT / 16;
    constexpr int KS = FIN / 32;
    if (wid >= Mtiles) return;
    const int l15 = lane & 15;
    const int quad = lane >> 4;
    const int v0 = wid * 16;

    v4f acc[NT];
#pragma unroll
    for (int nt = 0; nt < NT; nt++) acc[nt] = (v4f){0.f, 0.f, 0.f, 0.f};

    const unsigned short* xh = xhi + (v0 + l15) * FIN + quad * 8;
    const unsigned short* xl = xlo + (v0 + l15) * FIN + quad * 8;
    const unsigned short* wh = whi + l15 * FIN + quad * 8;
    const unsigned short* wl = wlo + l15 * FIN + quad * 8;
#pragma unroll
    for (int ks = 0; ks < KS; ks++) {
        short8 ah = *(const short8*)(xh + ks * 32);
        short8 al = *(const short8*)(xl + ks * 32);
#pragma unroll
        for (int nt = 0; nt < NT; nt++) {
            short8 bh = *(const short8*)(wh + nt * 16 * FIN + ks * 32);
            short8 bl = *(const short8*)(wl + nt * 16 * FIN + ks * 32);
            acc[nt] = __builtin_amdgcn_mfma_f32_16x16x32_bf16(ah, bh, acc[nt], 0, 0, 0);
            acc[nt] = __builtin_amdgcn_mfma_f32_16x16x32_bf16(ah, bl, acc[nt], 0, 0, 0);
            acc[nt] = __builtin_amdgcn_mfma_f32_16x16x32_bf16(al, bh, acc[nt], 0, 0, 0);
        }
    }
    float ps[4] = {0.f, 0.f, 0.f, 0.f}, pd[4] = {0.f, 0.f, 0.f, 0.f};
#pragma unroll
    for (int nt = 0; nt < NT; nt++) {
        float av = as[nt * 16 + l15];
        float dv = ad[nt * 16 + l15];
#pragma unroll
        for (int r = 0; r < 4; r++) {
            float c = acc[nt][r];
            h[(v0 + quad * 4 + r) * FOUT + nt * 16 + l15] = c;
            ps[r] += c * av;
            pd[r] += c * dv;
        }
    }
#pragma unroll
    for (int o = 8; o >= 1; o >>= 1) {
#pragma unroll
        for (int r = 0; r < 4; r++) {
            ps[r] += __shfl_xor(ps[r], o, 64);
            pd[r] += __shfl_xor(pd[r], o, 64);
        }
    }
    if (l15 == 0) {
#pragma unroll
        for (int r = 0; r < 4; r++) {
            hs[v0 + quad * 4 + r] = ps[r];
            hd[v0 + quad * 4 + r] = pd[r];
        }
    }
}

template <int FIN, int FOUT>
__global__ __launch_bounds__(256) void gemm_att_kernel(
        const unsigned short* __restrict__ xhi, const unsigned short* __restrict__ xlo,
        const unsigned short* __restrict__ whi, const unsigned short* __restrict__ wlo,
        const float* __restrict__ as, const float* __restrict__ ad, float* __restrict__ h,
        float* __restrict__ hs, float* __restrict__ hd, int Mtiles) {
    gemm_att_body<FIN, FOUT>(blockIdx.x * 4 + (threadIdx.x >> 6), threadIdx.x & 63, xhi, xlo,
                             whi, wlo, as, ad, h, hs, hd, Mtiles);
}

// ---------------- scatter (SB blocks) fused with gemm0 (rest) — independent work ----------------
__global__ __launch_bounds__(256) void scatter_gemm0_kernel(
        const int* __restrict__ src, const int* __restrict__ dst, int* __restrict__ cursor,
        int* __restrict__ col, int E, int SB,
        const unsigned short* __restrict__ xhi, const unsigned short* __restrict__ xlo,
        const unsigned short* __restrict__ whi, const unsigned short* __restrict__ wlo,
        const float* __restrict__ as, const float* __restrict__ ad, float* __restrict__ h,
        float* __restrict__ hs, float* __restrict__ hd, int Mtiles) {
    if (blockIdx.x < SB) {
        int e = blockIdx.x * 256 + threadIdx.x;
        if (e < E) {
            int p = atomicAdd(&cursor[dst[e]], 1);
            col[p] = src[e];
        }
    } else {
        gemm_att_body<64, 128>((blockIdx.x - SB) * 4 + (threadIdx.x >> 6), threadIdx.x & 63,
                               xhi, xlo, whi, wlo, as, ad, h, hs, hd, Mtiles);
    }
}

// ---------------- softmax-weighted aggregation; one wave per node, 4 nodes/block ----------------
template <int FOUT, bool RELU, bool SPLIT>
__global__ __launch_bounds__(256) void agg_kernel(
        const float* __restrict__ h, const float* __restrict__ hs, const float* __restrict__ hd,
        const int* __restrict__ rowptr, const int* __restrict__ col, const float* __restrict__ b,
        float* __restrict__ out, unsigned short* __restrict__ ohi,
        unsigned short* __restrict__ olo) {
    constexpr int FPT = FOUT / 64;
    constexpr int CAP = 128;  // deg ~ Poisson(32); overflow tail path covers >CAP. LDS = 4 KB.
    __shared__ float sw[4][CAP];
    __shared__ int ssv[4][CAP];
    const int w = threadIdx.x >> 6;
    const int lane = threadIdx.x & 63;
    const int v = blockIdx.x * 4 + w;
    float* swv = sw[w];
    int* ssvv = ssv[w];
    const int s0 = rowptr[v];
    const int deg = rowptr[v + 1] - s0;
    float acc[FPT];
#pragma unroll
    for (int i = 0; i < FPT; i++) acc[i] = 0.f;
    float inv = 0.f;
    if (deg > 0) {
        const float hdv = hd[v];
        float mt = -1e30f;
        for (int j = lane; j < deg; j += 64) {
            int sv = col[s0 + j];
            float e = hs[sv] + hdv;
            e = e > 0.f ? e : NEG_SLOPE * e;
            if (j < CAP) { ssvv[j] = sv; swv[j] = e; }
            mt = fmaxf(mt, e);
        }
        const float m = wave_red_max(mt);
        float st = 0.f;
        for (int j = lane; j < deg; j += 64) {
            float e;
            if (j < CAP) e = swv[j];
            else {
                int sv = col[s0 + j];
                e = hs[sv] + hdv;
                e = e > 0.f ? e : NEG_SLOPE * e;
            }
            float ww = __expf(e - m);
            if (j < CAP) swv[j] = ww;
            st += ww;
        }
        const float ssum = wave_red_sum(st);
        inv = 1.f / (ssum + 1e-16f);
        const int dmain = deg < CAP ? deg : CAP;
#pragma unroll 8
        for (int jj = 0; jj < dmain; jj++) {
            float ww = swv[jj];
            int sv = ssvv[jj];
            if (FPT == 2) {
                float2 hv = ((const float2*)(h + sv * FOUT))[lane];
                acc[0] += ww * hv.x;
                acc[1] += ww * hv.y;
            } else {
                acc[0] += ww * h[sv * FOUT + lane];
            }
        }
        for (int jj = CAP; jj < deg; jj++) {  // cold overflow path
            int sv = col[s0 + jj];
            float e = hs[sv] + hdv;
            e = e > 0.f ? e : NEG_SLOPE * e;
            float ww = __expf(e - m);
            if (FPT == 2) {
                float2 hv = ((const float2*)(h + sv * FOUT))[lane];
                acc[0] += ww * hv.x;
                acc[1] += ww * hv.y;
            } else {
                acc[0] += ww * h[sv * FOUT + lane];
            }
        }
    }
    float o[FPT];
#pragma unroll
    for (int i = 0; i < FPT; i++) {
        float bv = b[lane * FPT + i];
        o[i] = acc[i] * inv + bv;
        if (RELU) o[i] = fmaxf(o[i], 0.f);
    }
    if (SPLIT) {
        if (FPT == 2) {
            unsigned short h0, l0, h1, l1;
            split_bf(o[0], h0, l0);
            split_bf(o[1], h1, l1);
            ((ushort2*)ohi)[v * 64 + lane] = make_ushort2(h0, h1);
            ((ushort2*)olo)[v * 64 + lane] = make_ushort2(l0, l1);
        } else {
            unsigned short hb, lb;
            split_bf(o[0], hb, lb);
            ohi[v * FOUT + lane] = hb;
            olo[v * FOUT + lane] = lb;
        }
    } else {
        if (FPT == 2)
            ((float2*)out)[v * 64 + lane] = make_float2(o[0], o[1]);
        else
            out[v * FOUT + lane] = o[0];
    }
}

extern "C" void kernel_launch(void* const* d_in, const int* in_sizes, int n_in,
                              void* d_out, int out_size, void* d_ws, size_t ws_size,
                              hipStream_t stream) {
    const float* z   = (const float*)d_in[0];
    const int*   ei  = (const int*)d_in[1];
    const float* fcw = (const float*)d_in[2];
    const float* fcb = (const float*)d_in[3];
    const float* W0  = (const float*)d_in[4];
    const float* as0 = (const float*)d_in[5];
    const float* ad0 = (const float*)d_in[6];
    const float* b0  = (const float*)d_in[7];
    const float* W1  = (const float*)d_in[8];
    const float* as1 = (const float*)d_in[9];
    const float* ad1 = (const float*)d_in[10];
    const float* b1  = (const float*)d_in[11];
    const float* W2  = (const float*)d_in[12];
    const float* as2 = (const float*)d_in[13];
    const float* ad2 = (const float*)d_in[14];
    const float* b2  = (const float*)d_in[15];

    const int E = in_sizes[1] / 2;   // 640000
    const int R = in_sizes[3];       // N*64 = 1280000
    const int N = R / 64;            // 20000
    const int n0 = in_sizes[4];      // 128*64
    const int n1 = in_sizes[8];      // 128*128
    const int n2 = in_sizes[12];     // 64*128
    const int* src = ei;
    const int* dst = ei + E;

    // workspace carve (256B-aligned)
    char* p = (char*)d_ws;
    auto carve = [&](size_t bytes) {
        void* r = (void*)p;
        p += (bytes + 255) & ~(size_t)255;
        return r;
    };
    unsigned short* xhi = (unsigned short*)carve((size_t)N * 128 * 2);
    unsigned short* xlo = (unsigned short*)carve((size_t)N * 128 * 2);
    float* hbuf = (float*)carve((size_t)N * 128 * 4);
    float* hs = (float*)carve((size_t)N * 4);
    float* hd = (float*)carve((size_t)N * 4);
    unsigned short* whi = (unsigned short*)carve((size_t)(n0 + n1 + n2) * 2);
    unsigned short* wlo = (unsigned short*)carve((size_t)(n0 + n1 + n2) * 2);
    int* cnt = (int*)carve((size_t)N * 4);
    int* rowptr = (int*)carve((size_t)(N + 32) * 4);
    int* cursor = (int*)carve((size_t)N * 4);
    int* col = (int*)carve((size_t)E * 4);

    const int FB = R / 16;                    // 80000 fc blocks
    const int HB = (E + 255) / 256;           // 2500 hist blocks
    const int WB = (n0 + n1 + n2 + 255) / 256;  // 128 wsplit blocks
    const int Mtiles = N / 16;                // 1250
    const int GB = (Mtiles + 3) / 4;          // 313 gemm blocks
    const int SB = (E + 255) / 256;           // 2500 scatter blocks

    hipMemsetAsync(cnt, 0, (size_t)N * 4, stream);
    // fc + hist + wsplit (independent)
    mega1_kernel<<<FB + HB + WB, 256, 0, stream>>>(z, fcw, fcb, xhi, xlo, R, FB,
                                                   dst, cnt, E, HB,
                                                   W0, W1, W2, n0, n1, n2, whi, wlo);
    // rowptr/cursor
    scan_kernel<<<1, 1024, 0, stream>>>(cnt, rowptr, cursor, N);
    // scatter (needs scan) + layer-0 gemm/att (needs fc) — independent of each other
    scatter_gemm0_kernel<<<SB + GB, 256, 0, stream>>>(src, dst, cursor, col, E, SB,
                                                      xhi, xlo, whi, wlo, as0, ad0,
                                                      hbuf, hs, hd, Mtiles);
    // Layer 0 agg: [N,128], relu -> bf16 split
    agg_kernel<128, true, true><<<N / 4, 256, 0, stream>>>(hbuf, hs, hd, rowptr, col, b0,
                                                           nullptr, xhi, xlo);
    // Layer 1
    gemm_att_kernel<128, 128><<<GB, 256, 0, stream>>>(xhi, xlo, whi + n0, wlo + n0, as1, ad1,
                                                      hbuf, hs, hd, Mtiles);
    agg_kernel<128, true, true><<<N / 4, 256, 0, stream>>>(hbuf, hs, hd, rowptr, col, b1,
                                                           nullptr, xhi, xlo);
    // Layer 2
    gemm_att_kernel<128, 64><<<GB, 256, 0, stream>>>(xhi, xlo, whi + n0 + n1, wlo + n0 + n1,
                                                     as2, ad2, hbuf, hs, hd, Mtiles);
    agg_kernel<64, false, false><<<N / 4, 256, 0, stream>>>(hbuf, hs, hd, rowptr, col, b2,
                                                            (float*)d_out, nullptr, nullptr);
}

// Round 4
// 668.026 us; speedup vs baseline: 1.0329x; 1.0329x over previous
//
#include <hip/hip_runtime.h>

#define NEG_SLOPE 0.2f

typedef __attribute__((ext_vector_type(8))) short short8;
typedef __attribute__((ext_vector_type(4))) float v4f;
typedef _Float16 half2v __attribute__((ext_vector_type(2)));

__device__ __forceinline__ float wave_red_sum(float v) {
    for (int o = 32; o > 0; o >>= 1) v += __shfl_xor(v, o, 64);
    return v;
}
__device__ __forceinline__ float wave_red_max(float v) {
    for (int o = 32; o > 0; o >>= 1) v = fmaxf(v, __shfl_xor(v, o, 64));
    return v;
}
__device__ __forceinline__ unsigned short f2bf(float f) {
    union { float f; unsigned int u; } x; x.f = f;
    unsigned int r = x.u + 0x7fffu + ((x.u >> 16) & 1u);
    return (unsigned short)(r >> 16);
}
__device__ __forceinline__ float bf2f(unsigned short b) {
    union { unsigned int u; float f; } x; x.u = ((unsigned int)b) << 16;
    return x.f;
}
__device__ __forceinline__ void split_bf(float v, unsigned short& hi, unsigned short& lo) {
    hi = f2bf(v);
    lo = f2bf(v - bf2f(hi));
}

// ---------------- mega1: fc (FB blocks) + hist (HB blocks) + wsplit (WB blocks) ----------------
__global__ __launch_bounds__(256) void mega1_kernel(
        const float* __restrict__ z, const float* __restrict__ fcw, const float* __restrict__ fcb,
        unsigned short* __restrict__ xhi, unsigned short* __restrict__ xlo, int R, int FB,
        const int* __restrict__ dst, int* __restrict__ cnt, int E, int HB,
        const float* __restrict__ W0, const float* __restrict__ W1, const float* __restrict__ W2,
        int n0, int n1, int n2, unsigned short* __restrict__ whi, unsigned short* __restrict__ wlo) {
    const int b = blockIdx.x;
    if (b < FB) {
        // fc: x[r] = relu(dot64(z, fc_w[r]) + fc_b[r]) -> bf16 hi/lo. 16 lanes/row, float4 loads.
        int t = b * 256 + threadIdx.x;
        int r = t >> 4;
        int j = t & 15;
        if (r >= R) return;
        float4 wz = ((const float4*)z)[j];
        float4 ww = ((const float4*)fcw)[r * 16 + j];
        float p = wz.x * ww.x + wz.y * ww.y + wz.z * ww.z + wz.w * ww.w;
        p += __shfl_xor(p, 1, 64);
        p += __shfl_xor(p, 2, 64);
        p += __shfl_xor(p, 4, 64);
        p += __shfl_xor(p, 8, 64);
        if (j == 0) {
            float v = p + fcb[r];
            v = v > 0.f ? v : 0.f;
            unsigned short hi, lo;
            split_bf(v, hi, lo);
            xhi[r] = hi;
            xlo[r] = lo;
        }
    } else if (b < FB + HB) {
        int e = (b - FB) * 256 + threadIdx.x;
        if (e < E) atomicAdd(&cnt[dst[e]], 1);
    } else {
        int i = (b - FB - HB) * 256 + threadIdx.x;
        int ntot = n0 + n1 + n2;
        if (i >= ntot) return;
        float v;
        if (i < n0) v = W0[i];
        else if (i < n0 + n1) v = W1[i - n0];
        else v = W2[i - n0 - n1];
        unsigned short hi, lo;
        split_bf(v, hi, lo);
        whi[i] = hi;
        wlo[i] = lo;
    }
}

// ---------------- single-block exclusive scan over cnt[0..N) -> rowptr, cursor ----------------
__global__ __launch_bounds__(1024) void scan_kernel(const int* __restrict__ cnt,
                                                    int* __restrict__ rowptr,
                                                    int* __restrict__ cursor, int N) {
    constexpr int CH = 20;  // 1024*20 = 20480 >= N
    __shared__ int wsum[16];
    const int t = threadIdx.x;
    const int lane = t & 63, wid = t >> 6;
    const int base = t * CH;
    int loc[CH];
    int s = 0;
#pragma unroll
    for (int i = 0; i < CH; i++) {
        int idx = base + i;
        loc[i] = (idx < N) ? cnt[idx] : 0;
        s += loc[i];
    }
    int v = s;  // inclusive wave scan
    for (int off = 1; off < 64; off <<= 1) {
        int n = __shfl_up(v, off, 64);
        if (lane >= off) v += n;
    }
    if (lane == 63) wsum[wid] = v;
    __syncthreads();
    int woff = 0;
    for (int i = 0; i < wid; i++) woff += wsum[i];
    int excl = woff + v - s;
#pragma unroll
    for (int i = 0; i < CH; i++) {
        int idx = base + i;
        if (idx < N) { rowptr[idx] = excl; cursor[idx] = excl; }
        excl += loc[i];
    }
    if (t == 1023) rowptr[N] = excl;
}

// ---------------- gemm+att body (bf16-split MFMA, fragments straight from global) ----------------
// A-frag: A[m=lane&15][k=quad*8+j]; B-frag: B[k][n=lane&15]=W[n][k]; C/D: col=l15, row=quad*4+reg.
// h written as fp16 (feeds the bandwidth-bound agg gather); hs/hd stay fp32.
template <int FIN, int FOUT>
__device__ __forceinline__ void gemm_att_body(
        int wid, int lane, const unsigned short* __restrict__ xhi,
        const unsigned short* __restrict__ xlo, const unsigned short* __restrict__ whi,
        const unsigned short* __restrict__ wlo, const float* __restrict__ as,
        const float* __restrict__ ad, _Float16* __restrict__ h, float* __restrict__ hs,
        float* __restrict__ hd, int Mtiles) {
    constexpr int NT = FOUT / 16;
    constexpr int KS = FIN / 32;
    if (wid >= Mtiles) return;
    const int l15 = lane & 15;
    const int quad = lane >> 4;
    const int v0 = wid * 16;

    v4f acc[NT];
#pragma unroll
    for (int nt = 0; nt < NT; nt++) acc[nt] = (v4f){0.f, 0.f, 0.f, 0.f};

    const unsigned short* xh = xhi + (v0 + l15) * FIN + quad * 8;
    const unsigned short* xl = xlo + (v0 + l15) * FIN + quad * 8;
    const unsigned short* wh = whi + l15 * FIN + quad * 8;
    const unsigned short* wl = wlo + l15 * FIN + quad * 8;
#pragma unroll
    for (int ks = 0; ks < KS; ks++) {
        short8 ah = *(const short8*)(xh + ks * 32);
        short8 al = *(const short8*)(xl + ks * 32);
#pragma unroll
        for (int nt = 0; nt < NT; nt++) {
            short8 bh = *(const short8*)(wh + nt * 16 * FIN + ks * 32);
            short8 bl = *(const short8*)(wl + nt * 16 * FIN + ks * 32);
            acc[nt] = __builtin_amdgcn_mfma_f32_16x16x32_bf16(ah, bh, acc[nt], 0, 0, 0);
            acc[nt] = __builtin_amdgcn_mfma_f32_16x16x32_bf16(ah, bl, acc[nt], 0, 0, 0);
            acc[nt] = __builtin_amdgcn_mfma_f32_16x16x32_bf16(al, bh, acc[nt], 0, 0, 0);
        }
    }
    float ps[4] = {0.f, 0.f, 0.f, 0.f}, pd[4] = {0.f, 0.f, 0.f, 0.f};
#pragma unroll
    for (int nt = 0; nt < NT; nt++) {
        float av = as[nt * 16 + l15];
        float dv = ad[nt * 16 + l15];
#pragma unroll
        for (int r = 0; r < 4; r++) {
            float c = acc[nt][r];
            h[(v0 + quad * 4 + r) * FOUT + nt * 16 + l15] = (_Float16)c;
            ps[r] += c * av;
            pd[r] += c * dv;
        }
    }
#pragma unroll
    for (int o = 8; o >= 1; o >>= 1) {
#pragma unroll
        for (int r = 0; r < 4; r++) {
            ps[r] += __shfl_xor(ps[r], o, 64);
            pd[r] += __shfl_xor(pd[r], o, 64);
        }
    }
    if (l15 == 0) {
#pragma unroll
        for (int r = 0; r < 4; r++) {
            hs[v0 + quad * 4 + r] = ps[r];
            hd[v0 + quad * 4 + r] = pd[r];
        }
    }
}

template <int FIN, int FOUT>
__global__ __launch_bounds__(256) void gemm_att_kernel(
        const unsigned short* __restrict__ xhi, const unsigned short* __restrict__ xlo,
        const unsigned short* __restrict__ whi, const unsigned short* __restrict__ wlo,
        const float* __restrict__ as, const float* __restrict__ ad, _Float16* __restrict__ h,
        float* __restrict__ hs, float* __restrict__ hd, int Mtiles) {
    gemm_att_body<FIN, FOUT>(blockIdx.x * 4 + (threadIdx.x >> 6), threadIdx.x & 63, xhi, xlo,
                             whi, wlo, as, ad, h, hs, hd, Mtiles);
}

// ---------------- scatter (SB blocks) fused with gemm0 (rest) — independent work ----------------
__global__ __launch_bounds__(256) void scatter_gemm0_kernel(
        const int* __restrict__ src, const int* __restrict__ dst, int* __restrict__ cursor,
        int* __restrict__ col, int E, int SB,
        const unsigned short* __restrict__ xhi, const unsigned short* __restrict__ xlo,
        const unsigned short* __restrict__ whi, const unsigned short* __restrict__ wlo,
        const float* __restrict__ as, const float* __restrict__ ad, _Float16* __restrict__ h,
        float* __restrict__ hs, float* __restrict__ hd, int Mtiles) {
    if (blockIdx.x < SB) {
        int e = blockIdx.x * 256 + threadIdx.x;
        if (e < E) {
            int p = atomicAdd(&cursor[dst[e]], 1);
            col[p] = src[e];
        }
    } else {
        gemm_att_body<64, 128>((blockIdx.x - SB) * 4 + (threadIdx.x >> 6), threadIdx.x & 63,
                               xhi, xlo, whi, wlo, as, ad, h, hs, hd, Mtiles);
    }
}

// ---------------- softmax-weighted aggregation; one wave per node, 4 nodes/block ----------------
template <int FOUT, bool RELU, bool SPLIT>
__global__ __launch_bounds__(256) void agg_kernel(
        const _Float16* __restrict__ h, const float* __restrict__ hs, const float* __restrict__ hd,
        const int* __restrict__ rowptr, const int* __restrict__ col, const float* __restrict__ b,
        float* __restrict__ out, unsigned short* __restrict__ ohi,
        unsigned short* __restrict__ olo) {
    constexpr int FPT = FOUT / 64;
    constexpr int CAP = 128;  // deg ~ Binomial(E,1/N), mean 32, max ~56; overflow tail path anyway.
    __shared__ float sw[4][CAP];
    __shared__ int ssv[4][CAP];
    const int w = threadIdx.x >> 6;
    const int lane = threadIdx.x & 63;
    const int v = blockIdx.x * 4 + w;
    float* swv = sw[w];
    int* ssvv = ssv[w];
    const int s0 = rowptr[v];
    const int deg = rowptr[v + 1] - s0;
    float acc[FPT];
#pragma unroll
    for (int i = 0; i < FPT; i++) acc[i] = 0.f;
    float inv = 0.f;
    if (deg > 0) {
        const float hdv = hd[v];
        float mt = -1e30f;
        for (int j = lane; j < deg; j += 64) {
            int sv = col[s0 + j];
            float e = hs[sv] + hdv;
            e = e > 0.f ? e : NEG_SLOPE * e;
            if (j < CAP) { ssvv[j] = sv; swv[j] = e; }
            mt = fmaxf(mt, e);
        }
        const float m = wave_red_max(mt);
        float st = 0.f;
        for (int j = lane; j < deg; j += 64) {
            float e;
            if (j < CAP) e = swv[j];
            else {
                int sv = col[s0 + j];
                e = hs[sv] + hdv;
                e = e > 0.f ? e : NEG_SLOPE * e;
            }
            float ww = __expf(e - m);
            if (j < CAP) swv[j] = ww;
            st += ww;
        }
        const float ssum = wave_red_sum(st);
        inv = 1.f / (ssum + 1e-16f);
        const int dmain = deg < CAP ? deg : CAP;
#pragma unroll 8
        for (int jj = 0; jj < dmain; jj++) {
            float ww = swv[jj];
            int sv = ssvv[jj];
            if (FPT == 2) {
                half2v hv = ((const half2v*)(h + sv * FOUT))[lane];
                acc[0] += ww * (float)hv.x;
                acc[1] += ww * (float)hv.y;
            } else {
                acc[0] += ww * (float)h[sv * FOUT + lane];
            }
        }
        for (int jj = CAP; jj < deg; jj++) {  // cold overflow path
            int sv = col[s0 + jj];
            float e = hs[sv] + hdv;
            e = e > 0.f ? e : NEG_SLOPE * e;
            float ww = __expf(e - m);
            if (FPT == 2) {
                half2v hv = ((const half2v*)(h + sv * FOUT))[lane];
                acc[0] += ww * (float)hv.x;
                acc[1] += ww * (float)hv.y;
            } else {
                acc[0] += ww * (float)h[sv * FOUT + lane];
            }
        }
    }
    float o[FPT];
#pragma unroll
    for (int i = 0; i < FPT; i++) {
        float bv = b[lane * FPT + i];
        o[i] = acc[i] * inv + bv;
        if (RELU) o[i] = fmaxf(o[i], 0.f);
    }
    if (SPLIT) {
        if (FPT == 2) {
            unsigned short h0, l0, h1, l1;
            split_bf(o[0], h0, l0);
            split_bf(o[1], h1, l1);
            ((ushort2*)ohi)[v * 64 + lane] = make_ushort2(h0, h1);
            ((ushort2*)olo)[v * 64 + lane] = make_ushort2(l0, l1);
        } else {
            unsigned short hb, lb;
            split_bf(o[0], hb, lb);
            ohi[v * FOUT + lane] = hb;
            olo[v * FOUT + lane] = lb;
        }
    } else {
        if (FPT == 2)
            ((float2*)out)[v * 64 + lane] = make_float2(o[0], o[1]);
        else
            out[v * FOUT + lane] = o[0];
    }
}

extern "C" void kernel_launch(void* const* d_in, const int* in_sizes, int n_in,
                              void* d_out, int out_size, void* d_ws, size_t ws_size,
                              hipStream_t stream) {
    const float* z   = (const float*)d_in[0];
    const int*   ei  = (const int*)d_in[1];
    const float* fcw = (const float*)d_in[2];
    const float* fcb = (const float*)d_in[3];
    const float* W0  = (const float*)d_in[4];
    const float* as0 = (const float*)d_in[5];
    const float* ad0 = (const float*)d_in[6];
    const float* b0  = (const float*)d_in[7];
    const float* W1  = (const float*)d_in[8];
    const float* as1 = (const float*)d_in[9];
    const float* ad1 = (const float*)d_in[10];
    const float* b1  = (const float*)d_in[11];
    const float* W2  = (const float*)d_in[12];
    const float* as2 = (const float*)d_in[13];
    const float* ad2 = (const float*)d_in[14];
    const float* b2  = (const float*)d_in[15];

    const int E = in_sizes[1] / 2;   // 640000
    const int R = in_sizes[3];       // N*64 = 1280000
    const int N = R / 64;            // 20000
    const int n0 = in_sizes[4];      // 128*64
    const int n1 = in_sizes[8];      // 128*128
    const int n2 = in_sizes[12];     // 64*128
    const int* src = ei;
    const int* dst = ei + E;

    // workspace carve (256B-aligned)
    char* p = (char*)d_ws;
    auto carve = [&](size_t bytes) {
        void* r = (void*)p;
        p += (bytes + 255) & ~(size_t)255;
        return r;
    };
    unsigned short* xhi = (unsigned short*)carve((size_t)N * 128 * 2);
    unsigned short* xlo = (unsigned short*)carve((size_t)N * 128 * 2);
    _Float16* hbuf = (_Float16*)carve((size_t)N * 128 * 2);
    float* hs = (float*)carve((size_t)N * 4);
    float* hd = (float*)carve((size_t)N * 4);
    unsigned short* whi = (unsigned short*)carve((size_t)(n0 + n1 + n2) * 2);
    unsigned short* wlo = (unsigned short*)carve((size_t)(n0 + n1 + n2) * 2);
    int* cnt = (int*)carve((size_t)N * 4);
    int* rowptr = (int*)carve((size_t)(N + 32) * 4);
    int* cursor = (int*)carve((size_t)N * 4);
    int* col = (int*)carve((size_t)E * 4);

    const int FB = R / 16;                      // 80000 fc blocks
    const int HB = (E + 255) / 256;             // 2500 hist blocks
    const int WB = (n0 + n1 + n2 + 255) / 256;  // 128 wsplit blocks
    const int Mtiles = N / 16;                  // 1250
    const int GB = (Mtiles + 3) / 4;            // 313 gemm blocks
    const int SB = (E + 255) / 256;             // 2500 scatter blocks

    hipMemsetAsync(cnt, 0, (size_t)N * 4, stream);
    // fc + hist + wsplit (independent)
    mega1_kernel<<<FB + HB + WB, 256, 0, stream>>>(z, fcw, fcb, xhi, xlo, R, FB,
                                                   dst, cnt, E, HB,
                                                   W0, W1, W2, n0, n1, n2, whi, wlo);
    // rowptr/cursor
    scan_kernel<<<1, 1024, 0, stream>>>(cnt, rowptr, cursor, N);
    // scatter (needs scan) + layer-0 gemm/att (needs fc) — independent of each other
    scatter_gemm0_kernel<<<SB + GB, 256, 0, stream>>>(src, dst, cursor, col, E, SB,
                                                      xhi, xlo, whi, wlo, as0, ad0,
                                                      hbuf, hs, hd, Mtiles);
    // Layer 0 agg: [N,128], relu -> bf16 split
    agg_kernel<128, true, true><<<N / 4, 256, 0, stream>>>(hbuf, hs, hd, rowptr, col, b0,
                                                           nullptr, xhi, xlo);
    // Layer 1
    gemm_att_kernel<128, 128><<<GB, 256, 0, stream>>>(xhi, xlo, whi + n0, wlo + n0, as1, ad1,
                                                      hbuf, hs, hd, Mtiles);
    agg_kernel<128, true, true><<<N / 4, 256, 0, stream>>>(hbuf, hs, hd, rowptr, col, b1,
                                                           nullptr, xhi, xlo);
    // Layer 2
    gemm_att_kernel<128, 64><<<GB, 256, 0, stream>>>(xhi, xlo, whi + n0 + n1, wlo + n0 + n1,
                                                     as2, ad2, hbuf, hs, hd, Mtiles);
    agg_kernel<64, false, false><<<N / 4, 256, 0, stream>>>(hbuf, hs, hd, rowptr, col, b2,
                                                            (float*)d_out, nullptr, nullptr);
}